// Round 10
// baseline (564.368 us; speedup 1.0000x reference)
//
#include <hip/hip_runtime.h>

typedef __attribute__((ext_vector_type(8))) short short8;
typedef __attribute__((ext_vector_type(8))) unsigned short ushort8;
typedef __attribute__((ext_vector_type(4))) float f32x4;
typedef unsigned short ushort_t;

__device__ __forceinline__ ushort_t f2bf(float f) {
    unsigned u = __builtin_bit_cast(unsigned, f);
    u += 0x7fffu + ((u >> 16) & 1u);
    return (ushort_t)(u >> 16);
}
__device__ __forceinline__ float bf2f(ushort_t u) {
    unsigned v = ((unsigned)u) << 16;
    return __builtin_bit_cast(float, v);
}

__device__ __forceinline__ void load_lds16(const void* gp, void* lp) {
    __builtin_amdgcn_global_load_lds(
        (const __attribute__((address_space(1))) void*)gp,
        (__attribute__((address_space(3))) void*)lp, 16, 0, 0);
}

// MALL-direct stores (agent scope = executes at coherence point, bypasses the
// non-coherent per-XCD L2 on the write path). Consumers read fresh data from
// MALL because write-once rotation guarantees their L2s never hold the line.
__device__ __forceinline__ void st_f32(float* p, float v) {
    __hip_atomic_store(p, v, __ATOMIC_RELAXED, __HIP_MEMORY_SCOPE_AGENT);
}
__device__ __forceinline__ void st_u32(unsigned* p, unsigned v) {
    __hip_atomic_store(p, v, __ATOMIC_RELAXED, __HIP_MEMORY_SCOPE_AGENT);
}
__device__ __forceinline__ void st_u64(unsigned long long* p, unsigned long long v) {
    __hip_atomic_store(p, v, __ATOMIC_RELAXED, __HIP_MEMORY_SCOPE_AGENT);
}

// Grid barrier with NO cache maintenance: producers already stored to MALL.
// Arrive: one relaxed agent RMW. Spin: relaxed agent atomic LOADs (concurrent
// MALL reads -- no RMW serialization). s_barrier releases the block.
#define NWG 288
__device__ __forceinline__ void gsync(unsigned* ctr, int idx) {
    asm volatile("s_waitcnt vmcnt(0) lgkmcnt(0)" ::: "memory");
    if (threadIdx.x == 0) {
        __hip_atomic_fetch_add(&ctr[idx], 1u, __ATOMIC_RELAXED,
                               __HIP_MEMORY_SCOPE_AGENT);
        while (__hip_atomic_load(&ctr[idx], __ATOMIC_RELAXED,
                                 __HIP_MEMORY_SCOPE_AGENT) < NWG)
            __builtin_amdgcn_s_sleep(8);
    }
    __builtin_amdgcn_s_barrier();
    __builtin_amdgcn_sched_barrier(0);
    asm volatile("" ::: "memory");
}

// ---------------------------------------------------------------------------
// pool kernel (unchanged)
// ---------------------------------------------------------------------------
__global__ __launch_bounds__(256, 4) void pool_kernel(
    const float* __restrict__ x, ushort_t* __restrict__ AP) {
    int blk = blockIdx.x, tid = threadIdx.x;
    int bt = blk / 12, rc = blk % 12;
    int c = rc >> 2, igrp = rc & 3;
    int w = tid >> 6, lane = tid & 63;
    int i = igrp * 4 + w;
    int b = bt / 20, t = bt % 20;
    const float* base = x + (size_t)((b * 3 + c) * 20 + t) * 50176;

    f32x4 v[13];
    int ri = (lane >= 56) ? 1 : 0;
    int c4 = lane - 56 * ri;
    #pragma unroll
    for (int it = 0; it < 13; ++it) {
        if (it < 12 || lane < 16)
            v[it] = *(const f32x4*)(base + (16 * ri + i) * 224 + 4 * c4);
        else
            v[it] = (f32x4){0.f, 0.f, 0.f, 0.f};
        ri += 1; c4 += 8;
        if (c4 >= 56) { c4 -= 56; ri += 1; }
    }
    #pragma unroll
    for (int s = 1; s < 13; s <<= 1)
        #pragma unroll
        for (int j = 0; j + s < 13; j += 2 * s)
            v[j] += v[j + s];
    f32x4 acc = v[0];
    #pragma unroll
    for (int m = 4; m <= 32; m <<= 1) {
        acc[0] += __shfl_xor(acc[0], m);
        acc[1] += __shfl_xor(acc[1], m);
        acc[2] += __shfl_xor(acc[2], m);
        acc[3] += __shfl_xor(acc[3], m);
    }
    if (lane < 4) {
        ushort4 o;
        o.x = f2bf(acc[0] * (1.f / 196.f));
        o.y = f2bf(acc[1] * (1.f / 196.f));
        o.z = f2bf(acc[2] * (1.f / 196.f));
        o.w = f2bf(acc[3] * (1.f / 196.f));
        *(ushort4*)(AP + (size_t)bt * 768 + c * 256 + i * 16 + 4 * lane) = o;
    }
}

// ---------------------------------------------------------------------------
// wprep kernel (unchanged)
// ---------------------------------------------------------------------------
__global__ __launch_bounds__(256) void wprep_kernel(
    const float* __restrict__ w_qkv, const float* __restrict__ w_tf,
    const float* __restrict__ w_red, const float* __restrict__ conv_w,
    const float* __restrict__ w_tp, const float* __restrict__ b_tp,
    const float* __restrict__ b_tf, const float* __restrict__ cls,
    ushort_t* __restrict__ WQ, ushort_t* __restrict__ WF,
    ushort_t* __restrict__ WR, ushort_t* __restrict__ WCV,
    ushort_t* __restrict__ WTT, float* __restrict__ BC,
    float* __restrict__ GA) {
    __shared__ __align__(16) float smem[64 * 68];
    int blk = blockIdx.x, tid = threadIdx.x;
    if (blk < 6336) {
        long c = (long)blk * 256 + tid;
        const float* s; ushort_t* d; long i;
        if (c < 884736)       { s = w_qkv;  d = WQ;  i = c; }
        else if (c < 1179648) { s = w_tf;   d = WF;  i = c - 884736; }
        else if (c < 1474560) { s = w_red;  d = WR;  i = c - 1179648; }
        else                  { s = conv_w; d = WCV; i = c - 1474560; }
        i <<= 3;
        f32x4 a = *(const f32x4*)(s + i);
        f32x4 b = *(const f32x4*)(s + i + 4);
        ushort8 o;
        o[0] = f2bf(a[0]); o[1] = f2bf(a[1]); o[2] = f2bf(a[2]); o[3] = f2bf(a[3]);
        o[4] = f2bf(b[0]); o[5] = f2bf(b[1]); o[6] = f2bf(b[2]); o[7] = f2bf(b[3]);
        *(ushort8*)(d + i) = o;
    } else if (blk < 6912) {
        int tb = blk - 6336;
        int bi = tb / 24, bj = tb % 24;
        int r0 = (tid >> 4) << 2;
        int c0 = (tid & 15) << 2;
        #pragma unroll
        for (int rr = 0; rr < 4; ++rr) {
            f32x4 v = *(const f32x4*)(w_tp + (size_t)(bi * 64 + r0 + rr) * 1536 + bj * 64 + c0);
            smem[(r0 + rr) * 68 + c0 + 0] = v[0];
            smem[(r0 + rr) * 68 + c0 + 1] = v[1];
            smem[(r0 + rr) * 68 + c0 + 2] = v[2];
            smem[(r0 + rr) * 68 + c0 + 3] = v[3];
        }
        __syncthreads();
        #pragma unroll
        for (int rr = 0; rr < 4; ++rr) {
            int jj = r0 + rr;
            ushort4 o;
            o.x = f2bf(smem[(c0 + 0) * 68 + jj]);
            o.y = f2bf(smem[(c0 + 1) * 68 + jj]);
            o.z = f2bf(smem[(c0 + 2) * 68 + jj]);
            o.w = f2bf(smem[(c0 + 3) * 68 + jj]);
            *(ushort4*)(WTT + (size_t)(bj * 64 + jj) * 1536 + bi * 64 + c0) = o;
        }
    } else if (blk < 6952) {
        int cblk = blk - 6912;
        int b = cblk / 5, n = cblk % 5;
        size_t row = (size_t)(b * 25 + n * 5) * 1536;
        #pragma unroll
        for (int j = 0; j < 6; ++j) {
            int d = tid + j * 256;
            GA[row + d] = cls[n * 1536 + d];
        }
    } else {
        int bb = blk - 6952;
        int row = bb * 16 + (tid >> 4);
        int sub = tid & 15;
        float acc = 0.f;
        for (int j = 0; j < 96; ++j) {
            int k = sub + j * 16;
            acc += w_tf[(size_t)row * 1536 + k] * b_tp[k];
        }
        acc += __shfl_xor(acc, 1); acc += __shfl_xor(acc, 2);
        acc += __shfl_xor(acc, 4); acc += __shfl_xor(acc, 8);
        if (sub == 0) BC[row] = acc + b_tf[row];
    }
}

// ---------------------------------------------------------------------------
// device GEMM tile; epilogue uses MALL-direct stores (bf16 via lane-pairing)
// ---------------------------------------------------------------------------
template <int MT, bool OUT_BF16, bool HAS_BIAS, bool HAS_RES, bool CLS_SWAP, bool BUILD_G>
__device__ void gemm_tile(
    char* lds, int lane, int tn, int tm,
    const ushort_t* __restrict__ A, const ushort_t* __restrict__ B,
    void* __restrict__ Cv, const float* __restrict__ bias,
    const float* __restrict__ res, int M, int N, int K,
    float* __restrict__ g_out, const float* __restrict__ temb,
    const float* __restrict__ ts, const float* __restrict__ w_num,
    const float* __restrict__ b_num) {
    constexpr int BUFB = MT * 2048 + 8192;

    f32x4 acc[MT][4];
    #pragma unroll
    for (int m = 0; m < MT; ++m)
        #pragma unroll
        for (int n = 0; n < 4; ++n)
            acc[m][n] = (f32x4){0.f, 0.f, 0.f, 0.f};

    const int nK = K >> 6;
    const int rbase = lane >> 3, cc = lane & 7;

    auto stage = [&](int k0, int buf) {
        char* lA = lds + buf * BUFB;
        char* lB = lA + MT * 2048;
        #pragma unroll
        for (int j = 0; j < MT * 2; ++j) {
            int row = j * 8 + rbase;
            int cf = cc ^ (row & 7);
            int ga = tm * (MT * 16) + row; if (ga > M - 1) ga = M - 1;
            load_lds16(A + (size_t)ga * K + (k0 + cf * 8), lA + j * 1024);
        }
        #pragma unroll
        for (int j = 0; j < 8; ++j) {
            int row = j * 8 + rbase;
            int cf = cc ^ (row & 7);
            load_lds16(B + (size_t)(tn * 64 + row) * K + (k0 + cf * 8), lB + j * 1024);
        }
    };

    stage(0, 0);
    for (int t = 0; t < nK; ++t) {
        int cur = t & 1;
        if (t + 1 < nK) {
            stage((t + 1) << 6, cur ^ 1);
            if constexpr (MT == 2) asm volatile("s_waitcnt vmcnt(12)" ::: "memory");
            else                   asm volatile("s_waitcnt vmcnt(16)" ::: "memory");
        } else {
            asm volatile("s_waitcnt vmcnt(0)" ::: "memory");
        }
        __builtin_amdgcn_sched_barrier(0);
        const char* lA = lds + cur * BUFB;
        const char* lB = lA + MT * 2048;
        #pragma unroll
        for (int ks = 0; ks < 2; ++ks) {
            short8 av[MT], bv[4];
            const int rlo = lane & 15;
            const int chi = ks * 4 + (lane >> 4);
            #pragma unroll
            for (int m = 0; m < MT; ++m) {
                int r = m * 16 + rlo;
                av[m] = *(const short8*)(lA + r * 128 + ((chi ^ (r & 7)) << 4));
            }
            #pragma unroll
            for (int n = 0; n < 4; ++n) {
                int r = n * 16 + rlo;
                bv[n] = *(const short8*)(lB + r * 128 + ((chi ^ (r & 7)) << 4));
            }
            #pragma unroll
            for (int m = 0; m < MT; ++m)
                #pragma unroll
                for (int n = 0; n < 4; ++n)
                    acc[m][n] = __builtin_amdgcn_mfma_f32_16x16x32_bf16(
                        av[m], bv[n], acc[m][n], 0, 0, 0);
        }
    }

    const int c_l = lane & 15, r_q = (lane >> 4) * 4;
    #pragma unroll
    for (int m = 0; m < MT; ++m) {
        #pragma unroll
        for (int reg = 0; reg < 4; ++reg) {
            int r_ = tm * (MT * 16) + m * 16 + r_q + reg;
            if (r_ < M) {
                int r2 = r_;
                if (CLS_SWAP) {
                    int bb = r_ / 25, rem = r_ % 25;
                    if (rem % 5 == 0) r2 = bb * 25 + ((rem / 5 + 1) % 5) * 5;
                }
                #pragma unroll
                for (int n = 0; n < 4; ++n) {
                    int cc_ = tn * 64 + n * 16 + c_l;
                    float v = acc[m][n][reg];
                    if (HAS_BIAS) v += bias[cc_];
                    if (HAS_RES) v += res[(size_t)r_ * N + cc_];
                    if (OUT_BF16) {
                        // pair lanes (c_l even/odd) -> one 4B MALL store
                        unsigned my = (unsigned)f2bf(v);
                        unsigned other = __shfl_xor(my, 1);
                        if (!(lane & 1)) {
                            unsigned packed = my | (other << 16);
                            st_u32((unsigned*)((ushort_t*)Cv + ((size_t)r2 * N + cc_)), packed);
                        }
                    } else {
                        st_f32((float*)Cv + ((size_t)r2 * N + cc_), v);
                    }
                    if (BUILD_G) {
                        int b = r_ / 20, t = r_ % 20;
                        float gval = v + temb[t * 1536 + cc_] +
                                     ts[b] * w_num[cc_] + b_num[cc_];
                        st_f32(g_out + (size_t)(b * 25 + (t / 4) * 5 + (t % 4) + 1) * 1536 + cc_, gval);
                    }
                }
            }
        }
    }
}

// ---------------------------------------------------------------------------
// device LN over one row (64 lanes); 8B MALL stores
// ---------------------------------------------------------------------------
__device__ void ln_row64(const float* __restrict__ x,
                         const float* __restrict__ gamma,
                         const float* __restrict__ beta,
                         ushort_t* __restrict__ out, int lane) {
    f32x4 v[6];
    float s = 0.f, s2 = 0.f;
    #pragma unroll
    for (int j = 0; j < 6; ++j) {
        v[j] = *(const f32x4*)(x + lane * 4 + j * 256);
        #pragma unroll
        for (int e = 0; e < 4; ++e) { s += v[j][e]; s2 += v[j][e] * v[j][e]; }
    }
    #pragma unroll
    for (int m = 1; m < 64; m <<= 1) { s += __shfl_xor(s, m); s2 += __shfl_xor(s2, m); }
    float mean = s * (1.0f / 1536.0f);
    float var  = s2 * (1.0f / 1536.0f) - mean * mean;
    float rstd = rsqrtf(var + 1e-5f);
    #pragma unroll
    for (int j = 0; j < 6; ++j) {
        f32x4 gm = *(const f32x4*)(gamma + lane * 4 + j * 256);
        f32x4 bt = *(const f32x4*)(beta + lane * 4 + j * 256);
        unsigned long long u =
            (unsigned long long)f2bf((v[j][0] - mean) * rstd * gm[0] + bt[0]) |
            ((unsigned long long)f2bf((v[j][1] - mean) * rstd * gm[1] + bt[1]) << 16) |
            ((unsigned long long)f2bf((v[j][2] - mean) * rstd * gm[2] + bt[2]) << 32) |
            ((unsigned long long)f2bf((v[j][3] - mean) * rstd * gm[3] + bt[3]) << 48);
        st_u64((unsigned long long*)(out + lane * 4 + j * 256), u);
    }
}

// ---------------------------------------------------------------------------
// device attention task; 4B MALL stores
// ---------------------------------------------------------------------------
__device__ void attn_task(const ushort_t* __restrict__ qkv,
                          ushort_t* __restrict__ o, int gid, int l) {
    int h = gid % 12, gg = gid / 12;
    const ushort_t* basep = qkv + (size_t)gg * 5 * 4608 + h * 128 + 2 * l;
    float q[5][2], k[5][2], v[5][2];
    #pragma unroll
    for (int tt = 0; tt < 5; ++tt) {
        ushort2 qv = *(const ushort2*)(basep + tt * 4608);
        ushort2 kv = *(const ushort2*)(basep + tt * 4608 + 1536);
        ushort2 vv = *(const ushort2*)(basep + tt * 4608 + 3072);
        q[tt][0] = bf2f(qv.x); q[tt][1] = bf2f(qv.y);
        k[tt][0] = bf2f(kv.x); k[tt][1] = bf2f(kv.y);
        v[tt][0] = bf2f(vv.x); v[tt][1] = bf2f(vv.y);
    }
    float sc[5][5];
    #pragma unroll
    for (int i = 0; i < 5; ++i)
        #pragma unroll
        for (int j = 0; j < 5; ++j)
            sc[i][j] = q[i][0] * k[j][0] + q[i][1] * k[j][1];
    #pragma unroll
    for (int m = 1; m < 64; m <<= 1)
        #pragma unroll
        for (int i = 0; i < 5; ++i)
            #pragma unroll
            for (int j = 0; j < 5; ++j)
                sc[i][j] += __shfl_xor(sc[i][j], m);
    const float scale = 0.08838834764831845f;
    float a_[5][5];
    #pragma unroll
    for (int i = 0; i < 5; ++i) {
        float mx = -1e30f;
        #pragma unroll
        for (int j = 0; j < 5; ++j) mx = fmaxf(mx, sc[i][j]);
        float sum = 0.f;
        #pragma unroll
        for (int j = 0; j < 5; ++j) { a_[i][j] = __expf((sc[i][j] - mx) * scale); sum += a_[i][j]; }
        float inv = 1.0f / sum;
        #pragma unroll
        for (int j = 0; j < 5; ++j) a_[i][j] *= inv;
    }
    #pragma unroll
    for (int i = 0; i < 5; ++i) {
        float o0 = 0.f, o1 = 0.f;
        #pragma unroll
        for (int j = 0; j < 5; ++j) { o0 += a_[i][j] * v[j][0]; o1 += a_[i][j] * v[j][1]; }
        unsigned packed = (unsigned)f2bf(o0) | ((unsigned)f2bf(o1) << 16);
        st_u32((unsigned*)(o + (size_t)(gg * 5 + i) * 1536 + h * 128 + 2 * l), packed);
    }
}

// ---------------------------------------------------------------------------
// device head task (plain store; host reads after dispatch-end flush)
// ---------------------------------------------------------------------------
__device__ void head_task(const float* __restrict__ gfin, const float* __restrict__ xr,
                          const float* __restrict__ w_head, const float* __restrict__ b_head,
                          float* __restrict__ out, int b, int l) {
    const float* gv = gfin + (size_t)(b * 25 + 24) * 1536;
    const float* xv = xr + (size_t)(b * 20 + 19) * 1536;
    float acc[7] = {0, 0, 0, 0, 0, 0, 0};
    for (int d = l; d < 1536; d += 64) {
        float xval = gv[d] + xv[d];
        #pragma unroll
        for (int c = 0; c < 7; ++c) acc[c] += xval * w_head[c * 1536 + d];
    }
    #pragma unroll
    for (int c = 0; c < 7; ++c)
        #pragma unroll
        for (int m = 1; m < 64; m <<= 1) acc[c] += __shfl_xor(acc[c], m);
    if (l == 0) {
        #pragma unroll
        for (int c = 0; c < 7; ++c) out[b * 7 + c] = acc[c] + b_head[c];
    }
}

// ---------------------------------------------------------------------------
// MEGA kernel with write-once buffer rotation + fence-free barriers.
// ---------------------------------------------------------------------------
struct MegaArgs {
    const ushort_t *AP, *WQ, *WF, *WR, *WCV, *WTT;
    ushort_t *WC, *FBF;
    ushort_t *HN[4];
    ushort_t *QKV[4];
    ushort_t *OBF[4];
    float *G[5];
    float *BC, *XR;
    const float *conv_b, *b_red, *temb, *ts, *w_num, *b_num, *ln_g, *ln_b,
                *w_head, *b_head;
    float* out;
    unsigned* bar;
};

__global__ __launch_bounds__(64) void mega_kernel(MegaArgs a) {
    __shared__ __align__(16) char lds[32768];
    const int wg = blockIdx.x;
    const int lane = threadIdx.x;
    int bi = 0;

    // P0: Wc = WF @ WTT^T (576 tiles) ; f = AP @ WCV^T + conv_b (72 tiles)
    for (int task = wg; task < 648; task += NWG) {
        if (task < 576) {
            gemm_tile<4, true, false, false, false, false>(
                lds, lane, task % 24, task / 24, a.WF, a.WTT, a.WC,
                nullptr, nullptr, 1536, 1536, 1536,
                nullptr, nullptr, nullptr, nullptr, nullptr);
        } else {
            int t2 = task - 576;
            gemm_tile<4, true, true, false, false, false>(
                lds, lane, t2 % 24, t2 / 24, a.AP, a.WCV, a.FBF,
                a.conv_b, nullptr, 160, 1536, 768,
                nullptr, nullptr, nullptr, nullptr, nullptr);
        }
    }
    gsync(a.bar, bi++);

    // P1: xr = f @ WR^T + b_red (f32, 120 tiles) + BUILD_G epilogue -> G[0]
    if (wg < 120)
        gemm_tile<2, false, true, false, false, true>(
            lds, lane, wg % 24, wg / 24, a.FBF, a.WR, a.XR,
            a.b_red, nullptr, 160, 1536, 1536,
            a.G[0], a.temb, a.ts, a.w_num, a.b_num);
    gsync(a.bar, bi++);

    for (int it = 0; it < 4; ++it) {
        const float* gsrc = a.G[it];
        float* gdst = a.G[it + 1];
        ushort_t* hn = a.HN[it];
        ushort_t* qkv = a.QKV[it];
        ushort_t* obf = a.OBF[it];
        // P2: LN (200 rows)
        if (wg < 200)
            ln_row64(gsrc + (size_t)wg * 1536, a.ln_g, a.ln_b,
                     hn + (size_t)wg * 1536, lane);
        gsync(a.bar, bi++);
        // P3: qkv = HN @ WQ^T (288 tiles, one per WG)
        gemm_tile<4, true, false, false, false, false>(
            lds, lane, wg % 72, wg / 72, hn, a.WQ, qkv,
            nullptr, nullptr, 200, 4608, 1536,
            nullptr, nullptr, nullptr, nullptr, nullptr);
        gsync(a.bar, bi++);
        // P4: attention (480 tasks)
        attn_task(qkv, obf, wg, lane);
        if (wg < 192) attn_task(qkv, obf, wg + NWG, lane);
        gsync(a.bar, bi++);
        // P5: gdst = OBF @ WC^T + BC + gsrc, cls-swap (168 tiles)
        if (wg < 168)
            gemm_tile<2, false, true, true, true, false>(
                lds, lane, wg % 24, wg / 24, obf, a.WC, gdst,
                a.BC, gsrc, 200, 1536, 1536,
                nullptr, nullptr, nullptr, nullptr, nullptr);
        gsync(a.bar, bi++);
    }
    // P6: head (8 tasks)
    if (wg < 8)
        head_task(a.G[4], a.XR, a.w_head, a.b_head, a.out, wg, lane);
}

// ---------------------------------------------------------------------------
// Workspace layout (bytes)
// ---------------------------------------------------------------------------
#define OFF_WQ   0u          // 14155776
#define OFF_WF   14155776u   // 4718592
#define OFF_WR   18874368u   // 4718592
#define OFF_WCV  23592960u   // 2359296
#define OFF_WTT  25952256u   // 4718592
#define OFF_WC   30670848u   // 4718592
#define OFF_BC   35389440u   // 6144
#define OFF_AP   35395584u   // 245760
#define OFF_FBF  35641344u   // 491520
#define OFF_XR   36132864u   // 983040
#define OFF_G    37115904u   // 5 x 1228800 = 6144000
#define OFF_HN   43259904u   // 4 x 614400  = 2457600
#define OFF_QKV  45717504u   // 4 x 1843200 = 7372800
#define OFF_OBF  53090304u   // 4 x 614400  = 2457600
#define OFF_BAR  55547904u   // 128

extern "C" void kernel_launch(void* const* d_in, const int* in_sizes, int n_in,
                              void* d_out, int out_size, void* d_ws, size_t ws_size,
                              hipStream_t stream) {
    const float* x      = (const float*)d_in[0];
    const float* ts     = (const float*)d_in[1];
    const float* conv_w = (const float*)d_in[2];
    const float* conv_b = (const float*)d_in[3];
    const float* w_red  = (const float*)d_in[4];
    const float* b_red  = (const float*)d_in[5];
    const float* w_num  = (const float*)d_in[6];
    const float* b_num  = (const float*)d_in[7];
    const float* temb   = (const float*)d_in[8];
    const float* cls    = (const float*)d_in[9];
    const float* ln_g   = (const float*)d_in[10];
    const float* ln_b   = (const float*)d_in[11];
    const float* w_qkv  = (const float*)d_in[12];
    const float* w_tp   = (const float*)d_in[13];
    const float* b_tp   = (const float*)d_in[14];
    const float* w_tf   = (const float*)d_in[15];
    const float* b_tf   = (const float*)d_in[16];
    const float* w_head = (const float*)d_in[17];
    const float* b_head = (const float*)d_in[18];

    char* ws = (char*)d_ws;
    ushort_t* WQ  = (ushort_t*)(ws + OFF_WQ);
    ushort_t* WF  = (ushort_t*)(ws + OFF_WF);
    ushort_t* WR  = (ushort_t*)(ws + OFF_WR);
    ushort_t* WCV = (ushort_t*)(ws + OFF_WCV);
    ushort_t* WTT = (ushort_t*)(ws + OFF_WTT);
    ushort_t* WC  = (ushort_t*)(ws + OFF_WC);
    float*    BC  = (float*)(ws + OFF_BC);
    ushort_t* AP  = (ushort_t*)(ws + OFF_AP);
    ushort_t* FBF = (ushort_t*)(ws + OFF_FBF);
    float*    XR  = (float*)(ws + OFF_XR);
    unsigned* BAR = (unsigned*)(ws + OFF_BAR);

    (void)hipMemsetAsync(BAR, 0, 128, stream);

    // 1a) pool (x -> AP)
    pool_kernel<<<1920, 256, 0, stream>>>(x, AP);
    // 1b) weight prep (+ cls rows into G[0])
    wprep_kernel<<<7048, 256, 0, stream>>>(w_qkv, w_tf, w_red, conv_w, w_tp,
                                           b_tp, b_tf, cls,
                                           WQ, WF, WR, WCV, WTT, BC,
                                           (float*)(ws + OFF_G));
    // 2) mega-kernel
    MegaArgs ma;
    ma.AP = AP; ma.WQ = WQ; ma.WF = WF; ma.WR = WR; ma.WCV = WCV; ma.WTT = WTT;
    ma.WC = WC; ma.FBF = FBF;
    for (int i = 0; i < 4; ++i) {
        ma.HN[i]  = (ushort_t*)(ws + OFF_HN  + (size_t)i * 614400u);
        ma.QKV[i] = (ushort_t*)(ws + OFF_QKV + (size_t)i * 1843200u);
        ma.OBF[i] = (ushort_t*)(ws + OFF_OBF + (size_t)i * 614400u);
    }
    for (int i = 0; i < 5; ++i)
        ma.G[i] = (float*)(ws + OFF_G + (size_t)i * 1228800u);
    ma.BC = BC; ma.XR = XR;
    ma.conv_b = conv_b; ma.b_red = b_red; ma.temb = temb; ma.ts = ts;
    ma.w_num = w_num; ma.b_num = b_num; ma.ln_g = ln_g; ma.ln_b = ln_b;
    ma.w_head = w_head; ma.b_head = b_head;
    ma.out = (float*)d_out;
    ma.bar = BAR;
    mega_kernel<<<NWG, 64, 0, stream>>>(ma);
}

// Round 11
// 212.750 us; speedup vs baseline: 2.6527x; 2.6527x over previous
//
#include <hip/hip_runtime.h>

typedef __attribute__((ext_vector_type(8))) short short8;
typedef __attribute__((ext_vector_type(8))) unsigned short ushort8;
typedef __attribute__((ext_vector_type(4))) float f32x4;
typedef unsigned short ushort_t;

__device__ __forceinline__ ushort_t f2bf(float f) {
    unsigned u = __builtin_bit_cast(unsigned, f);
    u += 0x7fffu + ((u >> 16) & 1u);
    return (ushort_t)(u >> 16);
}
__device__ __forceinline__ float bf2f(ushort_t u) {
    unsigned v = ((unsigned)u) << 16;
    return __builtin_bit_cast(float, v);
}

__device__ __forceinline__ void load_lds16(const void* gp, void* lp) {
    __builtin_amdgcn_global_load_lds(
        (const __attribute__((address_space(1))) void*)gp,
        (__attribute__((address_space(3))) void*)lp, 16, 0, 0);
}

// ---------------------------------------------------------------------------
// pool kernel: wave = (bt,c,i). UNCONDITIONAL clamped loads (13 independent,
// batched in flight), OOB values zeroed after the load. No LDS, no barriers.
// ---------------------------------------------------------------------------
__global__ __launch_bounds__(256, 4) void pool_kernel(
    const float* __restrict__ x, ushort_t* __restrict__ AP) {
    int blk = blockIdx.x, tid = threadIdx.x;
    int bt = blk / 12, rc = blk % 12;
    int c = rc >> 2, igrp = rc & 3;
    int w = tid >> 6, lane = tid & 63;
    int i = igrp * 4 + w;
    int b = bt / 20, t = bt % 20;
    const float* base = x + (size_t)((b * 3 + c) * 20 + t) * 50176;

    f32x4 v[13];
    #pragma unroll
    for (int it = 0; it < 13; ++it) {
        int k = lane + it * 64;
        int kk = k < 784 ? k : 0;               // clamp address, keep load unconditional
        int ri = (kk * 9363) >> 19;             // kk / 56 (magic mul, exact on [0,783])
        int c4 = kk - ri * 56;
        v[it] = *(const f32x4*)(base + (16 * ri + i) * 224 + 4 * c4);
        if (k >= 784) v[it] = (f32x4){0.f, 0.f, 0.f, 0.f};
    }
    #pragma unroll
    for (int s = 1; s < 13; s <<= 1)
        #pragma unroll
        for (int j = 0; j + s < 13; j += 2 * s)
            v[j] += v[j + s];
    f32x4 acc = v[0];
    #pragma unroll
    for (int m = 4; m <= 32; m <<= 1) {
        acc[0] += __shfl_xor(acc[0], m);
        acc[1] += __shfl_xor(acc[1], m);
        acc[2] += __shfl_xor(acc[2], m);
        acc[3] += __shfl_xor(acc[3], m);
    }
    if (lane < 4) {
        ushort4 o;
        o.x = f2bf(acc[0] * (1.f / 196.f));
        o.y = f2bf(acc[1] * (1.f / 196.f));
        o.z = f2bf(acc[2] * (1.f / 196.f));
        o.w = f2bf(acc[3] * (1.f / 196.f));
        *(ushort4*)(AP + (size_t)bt * 768 + c * 256 + i * 16 + 4 * lane) = o;
    }
}

// ---------------------------------------------------------------------------
// wprep kernel (unchanged from round 4)
// ---------------------------------------------------------------------------
__global__ __launch_bounds__(256) void wprep_kernel(
    const float* __restrict__ w_qkv, const float* __restrict__ w_tf,
    const float* __restrict__ w_red, const float* __restrict__ conv_w,
    const float* __restrict__ w_tp, const float* __restrict__ b_tp,
    const float* __restrict__ b_tf, const float* __restrict__ cls,
    ushort_t* __restrict__ WQ, ushort_t* __restrict__ WF,
    ushort_t* __restrict__ WR, ushort_t* __restrict__ WCV,
    ushort_t* __restrict__ WTT, float* __restrict__ BC,
    float* __restrict__ GA) {
    __shared__ __align__(16) float smem[64 * 68];
    int blk = blockIdx.x, tid = threadIdx.x;
    if (blk < 6336) {
        long c = (long)blk * 256 + tid;
        const float* s; ushort_t* d; long i;
        if (c < 884736)       { s = w_qkv;  d = WQ;  i = c; }
        else if (c < 1179648) { s = w_tf;   d = WF;  i = c - 884736; }
        else if (c < 1474560) { s = w_red;  d = WR;  i = c - 1179648; }
        else                  { s = conv_w; d = WCV; i = c - 1474560; }
        i <<= 3;
        f32x4 a = *(const f32x4*)(s + i);
        f32x4 b = *(const f32x4*)(s + i + 4);
        ushort8 o;
        o[0] = f2bf(a[0]); o[1] = f2bf(a[1]); o[2] = f2bf(a[2]); o[3] = f2bf(a[3]);
        o[4] = f2bf(b[0]); o[5] = f2bf(b[1]); o[6] = f2bf(b[2]); o[7] = f2bf(b[3]);
        *(ushort8*)(d + i) = o;
    } else if (blk < 6912) {
        int tb = blk - 6336;
        int bi = tb / 24, bj = tb % 24;
        int r0 = (tid >> 4) << 2;
        int c0 = (tid & 15) << 2;
        #pragma unroll
        for (int rr = 0; rr < 4; ++rr) {
            f32x4 v = *(const f32x4*)(w_tp + (size_t)(bi * 64 + r0 + rr) * 1536 + bj * 64 + c0);
            smem[(r0 + rr) * 68 + c0 + 0] = v[0];
            smem[(r0 + rr) * 68 + c0 + 1] = v[1];
            smem[(r0 + rr) * 68 + c0 + 2] = v[2];
            smem[(r0 + rr) * 68 + c0 + 3] = v[3];
        }
        __syncthreads();
        #pragma unroll
        for (int rr = 0; rr < 4; ++rr) {
            int jj = r0 + rr;
            ushort4 o;
            o.x = f2bf(smem[(c0 + 0) * 68 + jj]);
            o.y = f2bf(smem[(c0 + 1) * 68 + jj]);
            o.z = f2bf(smem[(c0 + 2) * 68 + jj]);
            o.w = f2bf(smem[(c0 + 3) * 68 + jj]);
            *(ushort4*)(WTT + (size_t)(bj * 64 + jj) * 1536 + bi * 64 + c0) = o;
        }
    } else if (blk < 6952) {
        int cblk = blk - 6912;
        int b = cblk / 5, n = cblk % 5;
        size_t row = (size_t)(b * 25 + n * 5) * 1536;
        #pragma unroll
        for (int j = 0; j < 6; ++j) {
            int d = tid + j * 256;
            GA[row + d] = cls[n * 1536 + d];
        }
    } else {
        int bb = blk - 6952;
        int row = bb * 16 + (tid >> 4);
        int sub = tid & 15;
        float acc = 0.f;
        for (int j = 0; j < 96; ++j) {
            int k = sub + j * 16;
            acc += w_tf[(size_t)row * 1536 + k] * b_tp[k];
        }
        acc += __shfl_xor(acc, 1); acc += __shfl_xor(acc, 2);
        acc += __shfl_xor(acc, 4); acc += __shfl_xor(acc, 8);
        if (sub == 0) BC[row] = acc + b_tf[row];
    }
}

// ---------------------------------------------------------------------------
// bf16 MFMA GEMM: C[M,N] = A[M,K] @ B[N,K]^T (+bias)(+res); tile MT*16 x 64.
// KS = row stride (may differ from K extent for split-K). SPLITK: grid y
// encodes (tm, half); half 1 shifts A/B by K and writes to Cv2.
// ---------------------------------------------------------------------------
template <int MT, bool OUT_BF16, bool HAS_BIAS, bool HAS_RES, bool CLS_SWAP,
          bool BUILD_G, bool SPLITK>
__global__ __launch_bounds__(64) void gemm_kernel(
    const ushort_t* __restrict__ A, const ushort_t* __restrict__ B,
    void* __restrict__ Cv, void* __restrict__ Cv2,
    const float* __restrict__ bias, const float* __restrict__ res,
    int M, int N, int K, int KS,
    float* __restrict__ g_out, const float* __restrict__ temb,
    const float* __restrict__ ts, const float* __restrict__ w_num,
    const float* __restrict__ b_num) {
    constexpr int BUFB = MT * 2048 + 8192;
    __shared__ __align__(16) char lds[2 * BUFB];
    const int lane = threadIdx.x;
    const int tn = blockIdx.x;
    int tm = blockIdx.y;
    if (SPLITK) {
        int half = tm >> 2;
        tm &= 3;
        if (half) { A += K; B += K; Cv = Cv2; }
    }

    f32x4 acc[MT][4];
    #pragma unroll
    for (int m = 0; m < MT; ++m)
        #pragma unroll
        for (int n = 0; n < 4; ++n)
            acc[m][n] = (f32x4){0.f, 0.f, 0.f, 0.f};

    const int nK = K >> 6;
    const int rbase = lane >> 3, cc = lane & 7;

    auto stage = [&](int k0, int buf) {
        char* lA = lds + buf * BUFB;
        char* lB = lA + MT * 2048;
        #pragma unroll
        for (int j = 0; j < MT * 2; ++j) {
            int row = j * 8 + rbase;
            int cf = cc ^ (row & 7);
            int ga = tm * (MT * 16) + row; if (ga > M - 1) ga = M - 1;
            load_lds16(A + (size_t)ga * KS + (k0 + cf * 8), lA + j * 1024);
        }
        #pragma unroll
        for (int j = 0; j < 8; ++j) {
            int row = j * 8 + rbase;
            int cf = cc ^ (row & 7);
            load_lds16(B + (size_t)(tn * 64 + row) * KS + (k0 + cf * 8), lB + j * 1024);
        }
    };

    stage(0, 0);
    for (int t = 0; t < nK; ++t) {
        int cur = t & 1;
        if (t + 1 < nK) {
            stage((t + 1) << 6, cur ^ 1);
            if constexpr (MT == 2) asm volatile("s_waitcnt vmcnt(12)" ::: "memory");
            else                   asm volatile("s_waitcnt vmcnt(16)" ::: "memory");
        } else {
            asm volatile("s_waitcnt vmcnt(0)" ::: "memory");
        }
        __builtin_amdgcn_sched_barrier(0);
        const char* lA = lds + cur * BUFB;
        const char* lB = lA + MT * 2048;
        #pragma unroll
        for (int ks = 0; ks < 2; ++ks) {
            short8 av[MT], bv[4];
            const int rlo = lane & 15;
            const int chi = ks * 4 + (lane >> 4);
            #pragma unroll
            for (int m = 0; m < MT; ++m) {
                int r = m * 16 + rlo;
                av[m] = *(const short8*)(lA + r * 128 + ((chi ^ (r & 7)) << 4));
            }
            #pragma unroll
            for (int n = 0; n < 4; ++n) {
                int r = n * 16 + rlo;
                bv[n] = *(const short8*)(lB + r * 128 + ((chi ^ (r & 7)) << 4));
            }
            #pragma unroll
            for (int m = 0; m < MT; ++m)
                #pragma unroll
                for (int n = 0; n < 4; ++n)
                    acc[m][n] = __builtin_amdgcn_mfma_f32_16x16x32_bf16(
                        av[m], bv[n], acc[m][n], 0, 0, 0);
        }
    }

    const int c_l = lane & 15, r_q = (lane >> 4) * 4;
    #pragma unroll
    for (int m = 0; m < MT; ++m) {
        #pragma unroll
        for (int reg = 0; reg < 4; ++reg) {
            int r_ = tm * (MT * 16) + m * 16 + r_q + reg;
            if (r_ < M) {
                int r2 = r_;
                if (CLS_SWAP) {
                    int bb = r_ / 25, rem = r_ % 25;
                    if (rem % 5 == 0) r2 = bb * 25 + ((rem / 5 + 1) % 5) * 5;
                }
                #pragma unroll
                for (int n = 0; n < 4; ++n) {
                    int cc_ = tn * 64 + n * 16 + c_l;
                    float v = acc[m][n][reg];
                    if (HAS_BIAS) v += bias[cc_];
                    if (HAS_RES) v += res[(size_t)r_ * N + cc_];
                    if (OUT_BF16) ((ushort_t*)Cv)[(size_t)r2 * N + cc_] = f2bf(v);
                    else          ((float*)Cv)[(size_t)r2 * N + cc_] = v;
                    if (BUILD_G) {
                        int b = r_ / 20, t = r_ % 20;
                        float gval = v + temb[t * 1536 + cc_] +
                                     ts[b] * w_num[cc_] + b_num[cc_];
                        g_out[(size_t)(b * 25 + (t / 4) * 5 + (t % 4) + 1) * 1536 + cc_] = gval;
                    }
                }
            }
        }
    }
}

// ---------------------------------------------------------------------------
// LayerNorm over D=1536 -> bf16 (unchanged)
// ---------------------------------------------------------------------------
__global__ __launch_bounds__(256) void ln_kernel(
    const float* __restrict__ g, const float* __restrict__ gamma,
    const float* __restrict__ beta, ushort_t* __restrict__ hn) {
    int r = blockIdx.x, tid = threadIdx.x;
    const float* x = g + (size_t)r * 1536;
    float v[6], s = 0.f, s2 = 0.f;
    #pragma unroll
    for (int j = 0; j < 6; ++j) {
        v[j] = x[tid + j * 256];
        s += v[j]; s2 += v[j] * v[j];
    }
    #pragma unroll
    for (int m = 1; m < 64; m <<= 1) { s += __shfl_xor(s, m); s2 += __shfl_xor(s2, m); }
    __shared__ float red[8];
    int wid = tid >> 6;
    if ((tid & 63) == 0) { red[wid] = s; red[4 + wid] = s2; }
    __syncthreads();
    s  = red[0] + red[1] + red[2] + red[3];
    s2 = red[4] + red[5] + red[6] + red[7];
    float mean = s * (1.0f / 1536.0f);
    float var  = s2 * (1.0f / 1536.0f) - mean * mean;
    float rstd = rsqrtf(var + 1e-5f);
    #pragma unroll
    for (int j = 0; j < 6; ++j) {
        int d = tid + j * 256;
        float y = (v[j] - mean) * rstd * gamma[d] + beta[d];
        hn[(size_t)r * 1536 + d] = f2bf(y);
    }
}

// ---------------------------------------------------------------------------
// Attention: one wave per (group, head); sums split-K halves (f32 in).
// ---------------------------------------------------------------------------
__global__ __launch_bounds__(64) void attn_kernel(
    const float* __restrict__ qA, const float* __restrict__ qB,
    ushort_t* __restrict__ o) {
    int gid = blockIdx.x;
    int h = gid % 12, gg = gid / 12;
    int l = threadIdx.x;
    size_t off = (size_t)gg * 5 * 4608 + h * 128 + 2 * l;
    const float* b0 = qA + off;
    const float* b1 = qB + off;
    float q[5][2], k[5][2], v[5][2];
    #pragma unroll
    for (int tt = 0; tt < 5; ++tt) {
        float2 q0 = *(const float2*)(b0 + tt * 4608);
        float2 q1 = *(const float2*)(b1 + tt * 4608);
        float2 k0 = *(const float2*)(b0 + tt * 4608 + 1536);
        float2 k1 = *(const float2*)(b1 + tt * 4608 + 1536);
        float2 v0 = *(const float2*)(b0 + tt * 4608 + 3072);
        float2 v1 = *(const float2*)(b1 + tt * 4608 + 3072);
        q[tt][0] = q0.x + q1.x; q[tt][1] = q0.y + q1.y;
        k[tt][0] = k0.x + k1.x; k[tt][1] = k0.y + k1.y;
        v[tt][0] = v0.x + v1.x; v[tt][1] = v0.y + v1.y;
    }
    float sc[5][5];
    #pragma unroll
    for (int i = 0; i < 5; ++i)
        #pragma unroll
        for (int j = 0; j < 5; ++j)
            sc[i][j] = q[i][0] * k[j][0] + q[i][1] * k[j][1];
    #pragma unroll
    for (int m = 1; m < 64; m <<= 1)
        #pragma unroll
        for (int i = 0; i < 5; ++i)
            #pragma unroll
            for (int j = 0; j < 5; ++j)
                sc[i][j] += __shfl_xor(sc[i][j], m);
    const float scale = 0.08838834764831845f;
    float a_[5][5];
    #pragma unroll
    for (int i = 0; i < 5; ++i) {
        float mx = -1e30f;
        #pragma unroll
        for (int j = 0; j < 5; ++j) mx = fmaxf(mx, sc[i][j]);
        float sum = 0.f;
        #pragma unroll
        for (int j = 0; j < 5; ++j) { a_[i][j] = __expf((sc[i][j] - mx) * scale); sum += a_[i][j]; }
        float inv = 1.0f / sum;
        #pragma unroll
        for (int j = 0; j < 5; ++j) a_[i][j] *= inv;
    }
    #pragma unroll
    for (int i = 0; i < 5; ++i) {
        float o0 = 0.f, o1 = 0.f;
        #pragma unroll
        for (int j = 0; j < 5; ++j) { o0 += a_[i][j] * v[j][0]; o1 += a_[i][j] * v[j][1]; }
        ushort2 w; w.x = f2bf(o0); w.y = f2bf(o1);
        *(ushort2*)(o + (size_t)(gg * 5 + i) * 1536 + h * 128 + 2 * l) = w;
    }
}

// ---------------------------------------------------------------------------
// Head (unchanged)
// ---------------------------------------------------------------------------
__global__ __launch_bounds__(64) void head_kernel(
    const float* __restrict__ gfin, const float* __restrict__ xr,
    const float* __restrict__ w_head, const float* __restrict__ b_head,
    float* __restrict__ out) {
    int b = blockIdx.x, l = threadIdx.x;
    const float* gv = gfin + (size_t)(b * 25 + 24) * 1536;
    const float* xv = xr + (size_t)(b * 20 + 19) * 1536;
    float acc[7] = {0, 0, 0, 0, 0, 0, 0};
    for (int d = l; d < 1536; d += 64) {
        float xval = gv[d] + xv[d];
        #pragma unroll
        for (int c = 0; c < 7; ++c) acc[c] += xval * w_head[c * 1536 + d];
    }
    #pragma unroll
    for (int c = 0; c < 7; ++c)
        #pragma unroll
        for (int m = 1; m < 64; m <<= 1) acc[c] += __shfl_xor(acc[c], m);
    if (l == 0) {
        #pragma unroll
        for (int c = 0; c < 7; ++c) out[b * 7 + c] = acc[c] + b_head[c];
    }
}

// ---------------------------------------------------------------------------
// Workspace layout (bytes)
// ---------------------------------------------------------------------------
#define OFF_WQ    0u          // 14155776
#define OFF_WF    14155776u   // 4718592
#define OFF_WR    18874368u   // 4718592
#define OFF_WCV   23592960u   // 2359296
#define OFF_WTT   25952256u   // 4718592
#define OFF_WC    30670848u   // 4718592
#define OFF_BC    35389440u   // 6144
#define OFF_AP    35395584u   // 245760
#define OFF_FBF   35641344u   // 491520
#define OFF_XR    36132864u   // 983040
#define OFF_GA    37115904u   // 1228800
#define OFF_GB    38344704u   // 1228800
#define OFF_HN    39573504u   // 614400
#define OFF_QKV0  40187904u   // 3686400 (f32)
#define OFF_QKV1  43874304u   // 3686400 (f32)
#define OFF_OBF   47560704u   // 614400

extern "C" void kernel_launch(void* const* d_in, const int* in_sizes, int n_in,
                              void* d_out, int out_size, void* d_ws, size_t ws_size,
                              hipStream_t stream) {
    const float* x      = (const float*)d_in[0];
    const float* ts     = (const float*)d_in[1];
    const float* conv_w = (const float*)d_in[2];
    const float* conv_b = (const float*)d_in[3];
    const float* w_red  = (const float*)d_in[4];
    const float* b_red  = (const float*)d_in[5];
    const float* w_num  = (const float*)d_in[6];
    const float* b_num  = (const float*)d_in[7];
    const float* temb   = (const float*)d_in[8];
    const float* cls    = (const float*)d_in[9];
    const float* ln_g   = (const float*)d_in[10];
    const float* ln_b   = (const float*)d_in[11];
    const float* w_qkv  = (const float*)d_in[12];
    const float* w_tp   = (const float*)d_in[13];
    const float* b_tp   = (const float*)d_in[14];
    const float* w_tf   = (const float*)d_in[15];
    const float* b_tf   = (const float*)d_in[16];
    const float* w_head = (const float*)d_in[17];
    const float* b_head = (const float*)d_in[18];

    char* ws = (char*)d_ws;
    ushort_t* WQ   = (ushort_t*)(ws + OFF_WQ);
    ushort_t* WF   = (ushort_t*)(ws + OFF_WF);
    ushort_t* WR   = (ushort_t*)(ws + OFF_WR);
    ushort_t* WCV  = (ushort_t*)(ws + OFF_WCV);
    ushort_t* WTT  = (ushort_t*)(ws + OFF_WTT);
    ushort_t* WC   = (ushort_t*)(ws + OFF_WC);
    float*    BC   = (float*)(ws + OFF_BC);
    ushort_t* AP   = (ushort_t*)(ws + OFF_AP);
    ushort_t* FBF  = (ushort_t*)(ws + OFF_FBF);
    float*    XR   = (float*)(ws + OFF_XR);
    float*    GA   = (float*)(ws + OFF_GA);
    float*    GB   = (float*)(ws + OFF_GB);
    ushort_t* HN   = (ushort_t*)(ws + OFF_HN);
    float*    QKV0 = (float*)(ws + OFF_QKV0);
    float*    QKV1 = (float*)(ws + OFF_QKV1);
    ushort_t* OBF  = (ushort_t*)(ws + OFF_OBF);

    // 1a) pool (x -> AP)
    pool_kernel<<<1920, 256, 0, stream>>>(x, AP);
    // 1b) weight prep (+ cls rows into GA)
    wprep_kernel<<<7048, 256, 0, stream>>>(w_qkv, w_tf, w_red, conv_w, w_tp,
                                           b_tp, b_tf, cls,
                                           WQ, WF, WR, WCV, WTT, BC, GA);
    // 2) Wc = Wf @ Wt (bf16)
    gemm_kernel<4, true, false, false, false, false, false><<<dim3(24, 24), 64, 0, stream>>>(
        WF, WTT, WC, nullptr, nullptr, nullptr, 1536, 1536, 1536, 1536,
        nullptr, nullptr, nullptr, nullptr, nullptr);
    // 3) f = ap @ conv_w^T + conv_b (bf16)
    gemm_kernel<2, true, true, false, false, false, false><<<dim3(24, 5), 64, 0, stream>>>(
        AP, WCV, FBF, nullptr, conv_b, nullptr, 160, 1536, 768, 768,
        nullptr, nullptr, nullptr, nullptr, nullptr);
    // 4) xr = f @ w_red^T + b_red (f32) + build g rows (k>0)
    gemm_kernel<2, false, true, false, false, true, false><<<dim3(24, 5), 64, 0, stream>>>(
        FBF, WR, XR, nullptr, b_red, nullptr, 160, 1536, 1536, 1536,
        GA, temb, ts, w_num, b_num);

    float* gsrc = GA;
    float* gdst = GB;
    for (int it = 0; it < 4; ++it) {
        ln_kernel<<<200, 256, 0, stream>>>(gsrc, ln_g, ln_b, HN);
        // qkv split-K x2: halves to QKV0/QKV1 (f32), summed in attn
        gemm_kernel<4, false, false, false, false, false, true><<<dim3(72, 8), 64, 0, stream>>>(
            HN, WQ, QKV0, QKV1, nullptr, nullptr, 200, 4608, 768, 1536,
            nullptr, nullptr, nullptr, nullptr, nullptr);
        attn_kernel<<<480, 64, 0, stream>>>(QKV0, QKV1, OBF);
        gemm_kernel<2, false, true, true, true, false, false><<<dim3(24, 7), 64, 0, stream>>>(
            OBF, WC, gdst, nullptr, BC, gsrc, 200, 1536, 1536, 1536,
            nullptr, nullptr, nullptr, nullptr, nullptr);
        float* tmp = gsrc; gsrc = gdst; gdst = tmp;
    }
    head_kernel<<<8, 64, 0, stream>>>(gsrc, XR, w_head, b_head, (float*)d_out);
}